// Round 12
// baseline (713.618 us; speedup 1.0000x reference)
//
#include <hip/hip_runtime.h>
#include <math.h>

#define NN 50000
#define NE 800000
#define SLOTCAP 48   // Poisson(16) max over 50k nodes ~ 40; P(overflow) ~ 1e-10

typedef float f32x4 __attribute__((ext_vector_type(4)));
typedef short s16x8 __attribute__((ext_vector_type(8)));
typedef short s16x4 __attribute__((ext_vector_type(4)));
typedef unsigned int u32;

__device__ __forceinline__ short f2bf(float f) {
    union { float f; u32 u; } v; v.f = f;
    u32 u = v.u;
    u += 0x7FFF + ((u >> 16) & 1);   // round-to-nearest-even
    return (short)(u >> 16);
}

__device__ __forceinline__ float u2f(u32 u) {
    union { u32 u; float f; } v; v.u = u; return v.f;
}

__device__ __forceinline__ s16x8 cvt8(f32x4 a, f32x4 b) {
    s16x8 r;
    r[0] = f2bf(a[0]); r[1] = f2bf(a[1]); r[2] = f2bf(a[2]); r[3] = f2bf(a[3]);
    r[4] = f2bf(b[0]); r[5] = f2bf(b[1]); r[6] = f2bf(b[2]); r[7] = f2bf(b[3]);
    return r;
}

__device__ __forceinline__ float gelu_exact(float x) {
    return 0.5f * x * (1.0f + erff(x * 0.70710678118654752f));
}

// tanh-form GELU (certified r8)
__device__ __forceinline__ float gelu_fast(float x) {
    const float z = 1.5957691216f * x * (1.0f + 0.044715f * x * x);
    return x * __builtin_amdgcn_rcpf(1.0f + __expf(-z));
}

// ---- prep: nf -> bf16 copy + transpose-convert edge weights (r11 exact) ----
__global__ __launch_bounds__(256) void prep_e(
    const float* __restrict__ nf, const float* __restrict__ ew1,
    const float* __restrict__ ew2,
    short* __restrict__ nfh, short* __restrict__ ew1t, short* __restrict__ ew2t)
{
    int idx = blockIdx.x * 256 + threadIdx.x;
    if (idx < NN * 64) nfh[idx] = f2bf(nf[idx]);
    if (idx < 24576) {                       // e_w1 [192][128] -> [128][192]
        int k = idx >> 7, c = idx & 127;
        ew1t[c * 192 + k] = f2bf(ew1[idx]);
    } else if (idx < 32768) {                // e_w2 [128][64] -> [64][128]
        int i = idx - 24576; int k = i >> 6, c = i & 63;
        ew2t[c * 128 + k] = f2bf(ew2[i]);
    }
}

// ---- slot_build: per-edge returning atomic, latency hidden by 12.5k waves ----
__global__ __launch_bounds__(256) void slot_build(
    const int* __restrict__ ei, int* __restrict__ cnti, u32* __restrict__ slots)
{
    const int e = blockIdx.x * 256 + threadIdx.x;    // grid covers NE exactly
    const int dn = ei[NE + e];
    const int idx = atomicAdd(&cnti[dn], 1);
    if (idx < SLOTCAP) slots[(size_t)dn * SLOTCAP + idx] = (u32)e;
}

// ---- edge kernel: r11 certified dataflow; SLOTS=1 removes ALL atomics ----
template<bool SLOTS>
__global__ __launch_bounds__(256, 6) void edge_k(
    const short* __restrict__ nfh, const int* __restrict__ ei,
    const float* __restrict__ ef,
    const short* __restrict__ w1t, const float* __restrict__ b1,
    const short* __restrict__ w2t, const float* __restrict__ b2,
    const float* __restrict__ gamma, const float* __restrict__ beta,
    float* __restrict__ eout, float* __restrict__ agg, int* __restrict__ cnti)
{
    __shared__ short h_lds[64][136];         // 17408 B; aliased float[64][68]
    __shared__ short ef_lds[64][72];         // 9216 B; bf16 ef rows
    const int tid  = threadIdx.x;
    const int wave = tid >> 6, lane = tid & 63;
    const int lo = lane & 15, hi = lane >> 4;
    const int eb = blockIdx.x * 64 + wave * 16;

    const int ar0 = eb + lo;
    const int s0 = ei[ar0];
    const int d0 = ei[NE + ar0];

    const short* pS0 = nfh + (size_t)s0 * 64;
    const short* pD0 = nfh + (size_t)d0 * 64;
    const float* pE0 = ef + (size_t)ar0 * 64;
    const int o0 = hi * 8, o1 = 32 + hi * 8;

    f32x4 acc[8];
#pragma unroll
    for (int j = 0; j < 8; ++j)
#pragma unroll
        for (int q = 0; q < 4; ++q) acc[j][q] = 0.0f;

#define KSTEP_H(PTR, OFF, K0)                                                   \
    {                                                                           \
        s16x8 fa0 = *(const s16x8*)((PTR) + (OFF));                             \
        _Pragma("unroll")                                                       \
        for (int ct = 0; ct < 8; ++ct) {                                        \
            s16x8 b = *(const s16x8*)(w1t + (ct * 16 + lo) * 192 + (K0) + hi * 8); \
            acc[ct] = __builtin_amdgcn_mfma_f32_16x16x32_bf16(fa0, b, acc[ct], 0, 0, 0); \
        }                                                                       \
    }
#define KSTEP_E(OFF, K0, KO)                                                    \
    {                                                                           \
        f32x4 x0l = *(const f32x4*)(pE0 + (OFF));                               \
        f32x4 x0h = *(const f32x4*)(pE0 + (OFF) + 4);                           \
        s16x8 fa0 = cvt8(x0l, x0h);                                             \
        s16x4 flo, fhi;                                                         \
        flo[0]=fa0[0]; flo[1]=fa0[1]; flo[2]=fa0[2]; flo[3]=fa0[3];             \
        fhi[0]=fa0[4]; fhi[1]=fa0[5]; fhi[2]=fa0[6]; fhi[3]=fa0[7];             \
        *(s16x4*)&ef_lds[wave * 16 + lo][(KO) + hi * 8]     = flo;              \
        *(s16x4*)&ef_lds[wave * 16 + lo][(KO) + hi * 8 + 4] = fhi;              \
        _Pragma("unroll")                                                       \
        for (int ct = 0; ct < 8; ++ct) {                                        \
            s16x8 b = *(const s16x8*)(w1t + (ct * 16 + lo) * 192 + (K0) + hi * 8); \
            acc[ct] = __builtin_amdgcn_mfma_f32_16x16x32_bf16(fa0, b, acc[ct], 0, 0, 0); \
        }                                                                       \
    }

    KSTEP_H(pS0, o0, 0);      // k   0..31 : nf[src] 0..31
    KSTEP_H(pS0, o1, 32);     // k  32..63 : nf[src] 32..63
    KSTEP_H(pD0, o0, 64);     // k  64..95 : nf[dst] 0..31
    KSTEP_H(pD0, o1, 96);     // k  96..127: nf[dst] 32..63
    KSTEP_E(o0, 128, 0);      // k 128..159: ef 0..31  (+stash)
    KSTEP_E(o1, 160, 32);     // k 160..191: ef 32..63 (+stash)
#undef KSTEP_H
#undef KSTEP_E

    // bias + tanh GELU -> h_lds (bf16), certified C/D mapping
#pragma unroll
    for (int ct = 0; ct < 8; ++ct) {
        const int col = ct * 16 + lo;
        const float bb = b1[col];
#pragma unroll
        for (int r = 0; r < 4; ++r) {
            float x = acc[ct][r] + bb;
            h_lds[wave * 16 + hi * 4 + r][col] = f2bf(gelu_fast(x));
        }
    }
    // no barrier: all LDS traffic stays within this wave's 16-row stripe

    // ---- GEMM2: [16 x 128] @ [128 x 64] per wave, certified mappings ----
    f32x4 acc2[4];
#pragma unroll
    for (int j = 0; j < 4; ++j)
#pragma unroll
        for (int q = 0; q < 4; ++q) acc2[j][q] = 0.0f;
#pragma unroll
    for (int ks = 0; ks < 4; ++ks) {
        const int k0 = ks * 32 + hi * 8;
        s16x8 a0 = *(const s16x8*)&h_lds[wave * 16 + lo][k0];
#pragma unroll
        for (int ct = 0; ct < 4; ++ct) {
            s16x8 b = *(const s16x8*)(w2t + (ct * 16 + lo) * 128 + k0);
            acc2[ct] = __builtin_amdgcn_mfma_f32_16x16x32_bf16(a0, b, acc2[ct], 0, 0, 0);
        }
    }

    // write update u to LDS with the certified C/D mapping (alias h_lds as f32)
    float (*u_lds)[68] = (float (*)[68])h_lds;   // exact alias
#pragma unroll
    for (int ct = 0; ct < 4; ++ct)
#pragma unroll
        for (int r = 0; r < 4; ++r)
            u_lds[wave * 16 + hi * 4 + r][ct * 16 + lo] = acc2[ct][r];

    // ---- certified SERIAL epilogue: lane = output column ----
    const float b2v = b2[lane], gmv = gamma[lane], btv = beta[lane];
#pragma unroll 4
    for (int e = 0; e < 16; ++e) {
        const int er   = wave * 16 + e;              // block-local row
        const int erow = blockIdx.x * 64 + er;       // global edge row
        const float efv = u2f(((u32)(unsigned short)ef_lds[er][lane]) << 16);
        float o = u_lds[er][lane] + b2v + efv;
        float s = o, s2 = o * o;
#pragma unroll
        for (int m = 1; m < 64; m <<= 1) { s += __shfl_xor(s, m); s2 += __shfl_xor(s2, m); }
        const float mean = s * 0.015625f;
        const float var  = s2 * 0.015625f - mean * mean;
        const float rs   = rsqrtf(var + 1e-5f);
        const float out  = (o - mean) * rs * gmv + btv;
        eout[(size_t)erow * 64 + lane] = out;
        if (!SLOTS) {
            const int dn = ei[NE + erow];
            atomicAdd(&agg[(size_t)dn * 64 + lane], out);
            if (lane == 0) atomicAdd(&cnti[dn], 1);
        }
    }
}

// ---- node kernel: certified f32 VALU; SLOTS=1 gathers eout rows by index ----
template<bool SLOTS>
__global__ __launch_bounds__(256) void node_valu(
    const float* __restrict__ nf,
    const float* __restrict__ w1, const float* __restrict__ b1,
    const float* __restrict__ w2, const float* __restrict__ b2,
    const float* __restrict__ gamma, const float* __restrict__ beta,
    const float* __restrict__ agg, const int* __restrict__ cnti,
    const u32* __restrict__ slots, const float* __restrict__ eout,
    float* __restrict__ nout)
{
    __shared__ float xs[4][128];
    __shared__ float hs[4][128];
    const int wave = threadIdx.x >> 6, lane = threadIdx.x & 63;
    const int n = blockIdx.x * 4 + wave;         // grid covers exactly NN
    if (n >= NN) return;                          // whole-wave exit; no barriers here

    const int m = cnti[n];
    xs[wave][lane] = nf[(size_t)n * 64 + lane];
    if (SLOTS) {
        const int mm = min(m, SLOTCAP);
        float a = 0.0f;
        for (int i = 0; i < mm; ++i) {
            const u32 eid = slots[(size_t)n * SLOTCAP + i];   // wave-uniform
            a += eout[(size_t)eid * 64 + lane];               // coalesced 256B
        }
        xs[wave][64 + lane] = a / fmaxf((float)m, 1.0f);
    } else {
        xs[wave][64 + lane] = agg[(size_t)n * 64 + lane] / fmaxf((float)m, 1.0f);
    }

    float a0 = b1[lane], a1 = b1[64 + lane];
#pragma unroll 8
    for (int k = 0; k < 128; ++k) {
        const float xv = xs[wave][k];            // LDS broadcast
        a0 += xv * w1[k * 128 + lane];
        a1 += xv * w1[k * 128 + 64 + lane];
    }
    hs[wave][lane]      = gelu_exact(a0);
    hs[wave][64 + lane] = gelu_exact(a1);

    float o = b2[lane];
#pragma unroll 8
    for (int k = 0; k < 128; ++k)
        o += hs[wave][k] * w2[k * 64 + lane];
    o += nf[(size_t)n * 64 + lane];              // residual

    float s = o, s2 = o * o;
#pragma unroll
    for (int m2 = 1; m2 < 64; m2 <<= 1) { s += __shfl_xor(s, m2); s2 += __shfl_xor(s2, m2); }
    const float mean = s * 0.015625f;
    const float var  = s2 * 0.015625f - mean * mean;
    const float rs   = rsqrtf(var + 1e-5f);
    nout[(size_t)n * 64 + lane] = (o - mean) * rs * gamma[lane] + beta[lane];
}

extern "C" void kernel_launch(void* const* d_in, const int* in_sizes, int n_in,
                              void* d_out, int out_size, void* d_ws, size_t ws_size,
                              hipStream_t stream)
{
    const float* nf  = (const float*)d_in[0];
    const int*   ei  = (const int*)d_in[1];
    const float* ef  = (const float*)d_in[2];
    const float* ew1 = (const float*)d_in[3];
    const float* eb1 = (const float*)d_in[4];
    const float* ew2 = (const float*)d_in[5];
    const float* eb2 = (const float*)d_in[6];
    const float* nw1 = (const float*)d_in[7];
    const float* nb1 = (const float*)d_in[8];
    const float* nw2 = (const float*)d_in[9];
    const float* nb2 = (const float*)d_in[10];
    const float* eg  = (const float*)d_in[11];
    const float* ebt = (const float*)d_in[12];
    const float* ng  = (const float*)d_in[13];
    const float* nbt = (const float*)d_in[14];

    float* node_out = (float*)d_out;
    float* edge_out = node_out + (size_t)NN * 64;
    char*  ws    = (char*)d_ws;
    int*   cnti  = (int*)(ws);                  // 200000 B
    short* ew1t  = (short*)(ws + 200704);       // 49152 B
    short* ew2t  = (short*)(ws + 249856);       // 16384 B
    short* nfh   = (short*)(ws + 266240);       // 6.4 MB -> ends 6,666,240
    u32*   slots = (u32*)(ws + 6666240);        // 50000*48*4 = 9.6 MB -> ends 16,266,240
    float* agg   = node_out;                    // fallback path only

    const bool use_slots = ws_size >= (size_t)6666240 + (size_t)NN * SLOTCAP * 4;

    hipMemsetAsync(cnti, 0, (size_t)NN * 4, stream);
    prep_e<<<(NN * 64 + 255) / 256, 256, 0, stream>>>(nf, ew1, ew2, nfh, ew1t, ew2t);
    if (use_slots) {
        slot_build<<<NE / 256, 256, 0, stream>>>(ei, cnti, slots);
        edge_k<true><<<NE / 64, 256, 0, stream>>>(nfh, ei, ef, ew1t, eb1, ew2t, eb2,
                                                  eg, ebt, edge_out, agg, cnti);
        node_valu<true><<<NN / 4, 256, 0, stream>>>(nf, nw1, nb1, nw2, nb2, ng, nbt,
                                                    agg, cnti, slots, edge_out, node_out);
    } else {
        hipMemsetAsync(agg, 0, (size_t)NN * 64 * 4, stream);
        edge_k<false><<<NE / 64, 256, 0, stream>>>(nfh, ei, ef, ew1t, eb1, ew2t, eb2,
                                                   eg, ebt, edge_out, agg, cnti);
        node_valu<false><<<NN / 4, 256, 0, stream>>>(nf, nw1, nb1, nw2, nb2, ng, nbt,
                                                     agg, cnti, slots, edge_out, node_out);
    }
}

// Round 13
// 546.033 us; speedup vs baseline: 1.3069x; 1.3069x over previous
//
#include <hip/hip_runtime.h>
#include <math.h>

#define NN 50000
#define NE 800000

typedef float f32x4 __attribute__((ext_vector_type(4)));
typedef short s16x8 __attribute__((ext_vector_type(8)));
typedef short s16x4 __attribute__((ext_vector_type(4)));
typedef unsigned int u32;

__device__ __forceinline__ short f2bf(float f) {
    union { float f; u32 u; } v; v.f = f;
    u32 u = v.u;
    u += 0x7FFF + ((u >> 16) & 1);   // round-to-nearest-even
    return (short)(u >> 16);
}

__device__ __forceinline__ float u2f(u32 u) {
    union { u32 u; float f; } v; v.u = u; return v.f;
}

__device__ __forceinline__ s16x8 cvt8(f32x4 a, f32x4 b) {
    s16x8 r;
    r[0] = f2bf(a[0]); r[1] = f2bf(a[1]); r[2] = f2bf(a[2]); r[3] = f2bf(a[3]);
    r[4] = f2bf(b[0]); r[5] = f2bf(b[1]); r[6] = f2bf(b[2]); r[7] = f2bf(b[3]);
    return r;
}

__device__ __forceinline__ float gelu_exact(float x) {
    return 0.5f * x * (1.0f + erff(x * 0.70710678118654752f));
}

// tanh-form GELU (certified r8)
__device__ __forceinline__ float gelu_fast(float x) {
    const float z = 1.5957691216f * x * (1.0f + 0.044715f * x * x);
    return x * __builtin_amdgcn_rcpf(1.0f + __expf(-z));
}

// ---- prep: nf->bf16 + weights in MFMA-FRAGMENT ORDER ----
// w1f[(ks*8+ct)*512 + lane*8 + j] = bf16(ew1[(ks*32+(lane>>4)*8+j)*128 + ct*16+(lane&15)])
// -> each B-load instr in edge_k reads base + lane*16B : one contiguous 1KB chunk.
__global__ __launch_bounds__(256) void prep_e(
    const float* __restrict__ nf, const float* __restrict__ ew1,
    const float* __restrict__ ew2,
    short* __restrict__ nfh, short* __restrict__ w1f, short* __restrict__ w2f)
{
    int idx = blockIdx.x * 256 + threadIdx.x;
    if (idx < NN * 64) nfh[idx] = f2bf(nf[idx]);
    if (idx < 24576) {                       // w1f: 6 ks * 8 ct * 512
        const int m = idx >> 9, r = idx & 511;
        const int lane = r >> 3, j = r & 7;
        const int ks = m >> 3, ct = m & 7;
        const int k = ks * 32 + (lane >> 4) * 8 + j;
        const int c = ct * 16 + (lane & 15);
        w1f[idx] = f2bf(ew1[k * 128 + c]);
    } else if (idx < 32768) {                // w2f: 4 ks * 4 ct * 512
        const int i = idx - 24576;
        const int m = i >> 9, r = i & 511;
        const int lane = r >> 3, j = r & 7;
        const int ks = m >> 2, ct = m & 3;
        const int k = ks * 32 + (lane >> 4) * 8 + j;
        const int c = ct * 16 + (lane & 15);
        w2f[i] = f2bf(ew2[k * 64 + c]);
    }
}

// ---- edge kernel: r11 certified dataflow + fragment-ordered B loads ----
__global__ __launch_bounds__(256, 6) void edge_k(
    const short* __restrict__ nfh, const int* __restrict__ ei,
    const float* __restrict__ ef,
    const short* __restrict__ w1f, const float* __restrict__ b1,
    const short* __restrict__ w2f, const float* __restrict__ b2,
    const float* __restrict__ gamma, const float* __restrict__ beta,
    float* __restrict__ eout, float* __restrict__ agg, float* __restrict__ cnt)
{
    __shared__ short h_lds[64][136];         // 17408 B; aliased float[64][68]
    __shared__ short ef_lds[64][72];         // 9216 B; bf16 ef rows
    const int tid  = threadIdx.x;
    const int wave = tid >> 6, lane = tid & 63;
    const int lo = lane & 15, hi = lane >> 4;
    const int eb = blockIdx.x * 64 + wave * 16;

    const int ar0 = eb + lo;
    const int s0 = ei[ar0];
    const int d0 = ei[NE + ar0];

    const short* pS0 = nfh + (size_t)s0 * 64;
    const short* pD0 = nfh + (size_t)d0 * 64;
    const float* pE0 = ef + (size_t)ar0 * 64;
    const int o0 = hi * 8, o1 = 32 + hi * 8;

    f32x4 acc[8];
#pragma unroll
    for (int j = 0; j < 8; ++j)
#pragma unroll
        for (int q = 0; q < 4; ++q) acc[j][q] = 0.0f;

    // nf segments: direct bf16 gather; B from fragment-ordered table (coalesced)
#define KSTEP_H(PTR, OFF, KS)                                                   \
    {                                                                           \
        s16x8 fa0 = *(const s16x8*)((PTR) + (OFF));                             \
        _Pragma("unroll")                                                       \
        for (int ct = 0; ct < 8; ++ct) {                                        \
            s16x8 b = *(const s16x8*)(w1f + (((KS) * 8 + ct) << 9) + lane * 8); \
            acc[ct] = __builtin_amdgcn_mfma_f32_16x16x32_bf16(fa0, b, acc[ct], 0, 0, 0); \
        }                                                                       \
    }
#define KSTEP_E(OFF, KS, KO)                                                    \
    {                                                                           \
        f32x4 x0l = *(const f32x4*)(pE0 + (OFF));                               \
        f32x4 x0h = *(const f32x4*)(pE0 + (OFF) + 4);                           \
        s16x8 fa0 = cvt8(x0l, x0h);                                             \
        s16x4 flo, fhi;                                                         \
        flo[0]=fa0[0]; flo[1]=fa0[1]; flo[2]=fa0[2]; flo[3]=fa0[3];             \
        fhi[0]=fa0[4]; fhi[1]=fa0[5]; fhi[2]=fa0[6]; fhi[3]=fa0[7];             \
        *(s16x4*)&ef_lds[wave * 16 + lo][(KO) + hi * 8]     = flo;              \
        *(s16x4*)&ef_lds[wave * 16 + lo][(KO) + hi * 8 + 4] = fhi;              \
        _Pragma("unroll")                                                       \
        for (int ct = 0; ct < 8; ++ct) {                                        \
            s16x8 b = *(const s16x8*)(w1f + (((KS) * 8 + ct) << 9) + lane * 8); \
            acc[ct] = __builtin_amdgcn_mfma_f32_16x16x32_bf16(fa0, b, acc[ct], 0, 0, 0); \
        }                                                                       \
    }

    KSTEP_H(pS0, o0, 0);      // k   0..31 : nf[src] 0..31
    KSTEP_H(pS0, o1, 1);      // k  32..63 : nf[src] 32..63
    KSTEP_H(pD0, o0, 2);      // k  64..95 : nf[dst] 0..31
    KSTEP_H(pD0, o1, 3);      // k  96..127: nf[dst] 32..63
    KSTEP_E(o0, 4, 0);        // k 128..159: ef 0..31  (+stash)
    KSTEP_E(o1, 5, 32);       // k 160..191: ef 32..63 (+stash)
#undef KSTEP_H
#undef KSTEP_E

    // bias + tanh GELU -> h_lds (bf16), certified C/D mapping
#pragma unroll
    for (int ct = 0; ct < 8; ++ct) {
        const int col = ct * 16 + lo;
        const float bb = b1[col];
#pragma unroll
        for (int r = 0; r < 4; ++r) {
            float x = acc[ct][r] + bb;
            h_lds[wave * 16 + hi * 4 + r][col] = f2bf(gelu_fast(x));
        }
    }
    // no barrier: all LDS traffic stays within this wave's 16-row stripe

    // ---- GEMM2: [16 x 128] @ [128 x 64] per wave, fragment-ordered B ----
    f32x4 acc2[4];
#pragma unroll
    for (int j = 0; j < 4; ++j)
#pragma unroll
        for (int q = 0; q < 4; ++q) acc2[j][q] = 0.0f;
#pragma unroll
    for (int ks = 0; ks < 4; ++ks) {
        const int k0 = ks * 32 + hi * 8;
        s16x8 a0 = *(const s16x8*)&h_lds[wave * 16 + lo][k0];
#pragma unroll
        for (int ct = 0; ct < 4; ++ct) {
            s16x8 b = *(const s16x8*)(w2f + (((ks) * 4 + ct) << 9) + lane * 8);
            acc2[ct] = __builtin_amdgcn_mfma_f32_16x16x32_bf16(a0, b, acc2[ct], 0, 0, 0);
        }
    }

    // write update u to LDS with the certified C/D mapping (alias h_lds as f32)
    float (*u_lds)[68] = (float (*)[68])h_lds;   // exact alias
#pragma unroll
    for (int ct = 0; ct < 4; ++ct)
#pragma unroll
        for (int r = 0; r < 4; ++r)
            u_lds[wave * 16 + hi * 4 + r][ct * 16 + lo] = acc2[ct][r];

    // ---- certified SERIAL epilogue: lane = output column (atomic agg, r11) ----
    const float b2v = b2[lane], gmv = gamma[lane], btv = beta[lane];
#pragma unroll 4
    for (int e = 0; e < 16; ++e) {
        const int er   = wave * 16 + e;              // block-local row
        const int erow = blockIdx.x * 64 + er;       // global edge row
        const float efv = u2f(((u32)(unsigned short)ef_lds[er][lane]) << 16);
        float o = u_lds[er][lane] + b2v + efv;
        float s = o, s2 = o * o;
#pragma unroll
        for (int m = 1; m < 64; m <<= 1) { s += __shfl_xor(s, m); s2 += __shfl_xor(s2, m); }
        const float mean = s * 0.015625f;
        const float var  = s2 * 0.015625f - mean * mean;
        const float rs   = rsqrtf(var + 1e-5f);
        const float out  = (o - mean) * rs * gmv + btv;
        eout[(size_t)erow * 64 + lane] = out;
        const int dn = ei[NE + erow];
        atomicAdd(&agg[(size_t)dn * 64 + lane], out);
        if (lane == 0) atomicAdd(&cnt[dn], 1.0f);
    }
}

// ---- node kernel: r11 certified form, verbatim ----
__global__ __launch_bounds__(256) void node_valu(
    const float* __restrict__ nf,
    const float* __restrict__ w1, const float* __restrict__ b1,
    const float* __restrict__ w2, const float* __restrict__ b2,
    const float* __restrict__ gamma, const float* __restrict__ beta,
    const float* __restrict__ agg, const float* __restrict__ cnt,
    float* __restrict__ nout)
{
    __shared__ float xs[4][128];
    __shared__ float hs[4][128];
    const int wave = threadIdx.x >> 6, lane = threadIdx.x & 63;
    const int n = blockIdx.x * 4 + wave;         // grid covers exactly NN
    if (n >= NN) return;                          // whole-wave exit; no barriers here

    const float ic = 1.0f / fmaxf(cnt[n], 1.0f);
    xs[wave][lane]      = nf[(size_t)n * 64 + lane];
    xs[wave][64 + lane] = agg[(size_t)n * 64 + lane] * ic;

    float a0 = b1[lane], a1 = b1[64 + lane];
#pragma unroll 8
    for (int k = 0; k < 128; ++k) {
        const float xv = xs[wave][k];            // LDS broadcast
        a0 += xv * w1[k * 128 + lane];
        a1 += xv * w1[k * 128 + 64 + lane];
    }
    hs[wave][lane]      = gelu_exact(a0);
    hs[wave][64 + lane] = gelu_exact(a1);

    float o = b2[lane];
#pragma unroll 8
    for (int k = 0; k < 128; ++k)
        o += hs[wave][k] * w2[k * 64 + lane];
    o += nf[(size_t)n * 64 + lane];              // residual

    float s = o, s2 = o * o;
#pragma unroll
    for (int m = 1; m < 64; m <<= 1) { s += __shfl_xor(s, m); s2 += __shfl_xor(s2, m); }
    const float mean = s * 0.015625f;
    const float var  = s2 * 0.015625f - mean * mean;
    const float rs   = rsqrtf(var + 1e-5f);
    nout[(size_t)n * 64 + lane] = (o - mean) * rs * gamma[lane] + beta[lane];
}

extern "C" void kernel_launch(void* const* d_in, const int* in_sizes, int n_in,
                              void* d_out, int out_size, void* d_ws, size_t ws_size,
                              hipStream_t stream)
{
    const float* nf  = (const float*)d_in[0];
    const int*   ei  = (const int*)d_in[1];
    const float* ef  = (const float*)d_in[2];
    const float* ew1 = (const float*)d_in[3];
    const float* eb1 = (const float*)d_in[4];
    const float* ew2 = (const float*)d_in[5];
    const float* eb2 = (const float*)d_in[6];
    const float* nw1 = (const float*)d_in[7];
    const float* nb1 = (const float*)d_in[8];
    const float* nw2 = (const float*)d_in[9];
    const float* nb2 = (const float*)d_in[10];
    const float* eg  = (const float*)d_in[11];
    const float* ebt = (const float*)d_in[12];
    const float* ng  = (const float*)d_in[13];
    const float* nbt = (const float*)d_in[14];

    float* node_out = (float*)d_out;
    float* edge_out = node_out + (size_t)NN * 64;
    char*  ws   = (char*)d_ws;
    float* cnt  = (float*)(ws);             // 200000 B
    short* w1f  = (short*)(ws + 200704);    // 49152 B
    short* w2f  = (short*)(ws + 249856);    // 16384 B
    short* nfh  = (short*)(ws + 266240);    // 6.4 MB
    float* agg  = node_out;                 // reuse node_out region as agg accumulator

    hipMemsetAsync(agg, 0, (size_t)NN * 64 * 4, stream);
    hipMemsetAsync(cnt, 0, (size_t)NN * 4, stream);
    prep_e<<<(NN * 64 + 255) / 256, 256, 0, stream>>>(nf, ew1, ew2, nfh, w1f, w2f);
    edge_k<<<NE / 64, 256, 0, stream>>>(nfh, ei, ef, w1f, eb1, w2f, eb2, eg, ebt,
                                        edge_out, agg, cnt);
    node_valu<<<NN / 4, 256, 0, stream>>>(nf, nw1, nb1, nw2, nb2, ng, nbt,
                                          agg, cnt, node_out);
}